// Round 1
// baseline (258.557 us; speedup 1.0000x reference)
//
#include <hip/hip_runtime.h>
#include <math.h>

// ExodusNeuron: per-(b,n) sequential scan over T with spike threshold/reset.
// x: (B=32, T=2048, N=512, 1) fp32; weight: (1,1) fp32; out: (B,T,N,1) fp32.
//
// R4: direct global<->register streaming, no LDS, no barriers.
//   R3 (producer/consumer, 82us kernel) was latency/serialization-bound:
//   VALUBusy 10.7%, HBM 30% of peak. The LDS round-trip + 64 barrier
//   rendezvous per block serialized producer latency tails with the
//   single consumer wave's dependent-chain tails.
//   There are exactly B*N = 16384 sequences = 256 waves -> 1 wave/CU.
//   Latency must be hidden by ILP, not TLP: double-buffered REGISTER
//   prefetch (32 steps = 8KB in flight/wave > ~5KB Little's-law need).
//   Loads for tile t+1 issue before compute of tile t; consumers of the
//   buffer are a full tile downstream so the compiler emits counted
//   (non-zero) vmcnt waits. Spike stores are nontemporal (write-once
//   stream) to keep L3 for the input.
//
// Numerics MUST match numpy's fp32 rounding exactly (outputs are 0/1 spikes;
// a flipped spike = absmax 1.0): separate rounded mul/add (no FMA), and
// alpha = correctly-rounded float of exp(double(float(-0.05))).
// fire ? __fsub_rn(va,1.0f) : va is bitwise identical to va - spk.
// R0-R3 all passed with absmax == 0.0 — do not change the arithmetic.

constexpr int B_ = 32;
constexpr int T_ = 2048;
constexpr int N_ = 512;
constexpr int TILE = 32;             // time steps per register tile
constexpr int NT = T_ / TILE;        // 64 tiles (even -> clean 2x unroll)

__global__ __launch_bounds__(64, 1)
void exodus_direct_kernel(const float* __restrict__ x,
                          const float* __restrict__ wptr,
                          float* __restrict__ out) {
    const int blk  = blockIdx.x;          // 0..255
    const int b    = blk >> 3;            // 0..31
    const int n0   = (blk & 7) * 64;      // 0,64,...,448
    const int lane = threadIdx.x;         // 0..63 (block = 1 wave)

    const size_t base = (size_t)b * T_ * N_ + (size_t)n0 + lane;
    const float* __restrict__ xp = x + base;
    float* __restrict__ op = out + base;

    const float w = wptr[0];
    const float alpha = (float)exp((double)(-1.0f / 20.0f));

    float bufA[TILE], bufB[TILE];

    // prologue: stage tile 0 into registers
#pragma unroll
    for (int i = 0; i < TILE; ++i) bufA[i] = xp[(size_t)i * N_];

    float vsyn = 0.0f, vmem = 0.0f;

    for (int t = 0; t < NT; t += 2) {
        // prefetch tile t+1 -> bufB (t+1 <= 63 always: NT even)
        {
            const float* __restrict__ g = xp + (size_t)(t + 1) * TILE * N_;
#pragma unroll
            for (int i = 0; i < TILE; ++i) bufB[i] = g[(size_t)i * N_];
        }
        // compute tile t from bufA
        {
            float* __restrict__ o = op + (size_t)t * TILE * N_;
#pragma unroll
            for (int j = 0; j < TILE; ++j) {
                const float i_t = __fmul_rn(bufA[j], w);
                vsyn = __fadd_rn(__fmul_rn(alpha, vsyn), i_t);
                const float va = __fadd_rn(__fmul_rn(alpha, vmem), vsyn);
                const bool fire = (va >= 1.0f);
                __builtin_nontemporal_store(fire ? 1.0f : 0.0f,
                                            o + (size_t)j * N_);
                vmem = fire ? __fsub_rn(va, 1.0f) : va;   // == va - spk
            }
        }
        // prefetch tile t+2 -> bufA
        if (t + 2 < NT) {
            const float* __restrict__ g = xp + (size_t)(t + 2) * TILE * N_;
#pragma unroll
            for (int i = 0; i < TILE; ++i) bufA[i] = g[(size_t)i * N_];
        }
        // compute tile t+1 from bufB
        {
            float* __restrict__ o = op + (size_t)(t + 1) * TILE * N_;
#pragma unroll
            for (int j = 0; j < TILE; ++j) {
                const float i_t = __fmul_rn(bufB[j], w);
                vsyn = __fadd_rn(__fmul_rn(alpha, vsyn), i_t);
                const float va = __fadd_rn(__fmul_rn(alpha, vmem), vsyn);
                const bool fire = (va >= 1.0f);
                __builtin_nontemporal_store(fire ? 1.0f : 0.0f,
                                            o + (size_t)j * N_);
                vmem = fire ? __fsub_rn(va, 1.0f) : va;   // == va - spk
            }
        }
    }
}

extern "C" void kernel_launch(void* const* d_in, const int* in_sizes, int n_in,
                              void* d_out, int out_size, void* d_ws, size_t ws_size,
                              hipStream_t stream) {
    const float* x = (const float*)d_in[0];
    const float* w = (const float*)d_in[1];
    float* out = (float*)d_out;

    dim3 grid(256);    // one wave per CU; 64 sequences per block
    dim3 block(64);
    hipLaunchKernelGGL(exodus_direct_kernel, grid, block, 0, stream, x, w, out);
}

// Round 2
// 253.218 us; speedup vs baseline: 1.0211x; 1.0211x over previous
//
#include <hip/hip_runtime.h>
#include <math.h>

// ExodusNeuron: per-(b,n) sequential scan over T with spike threshold/reset.
// x: (B=32, T=2048, N=512, 1) fp32; weight: (1,1) fp32; out: (B,T,N,1) fp32.
//
// R5: asm-controlled streaming pipeline (1 wave/CU, 1 sequence/lane).
//   R4 (C-level register double-buffer) FAILED at 102us: VGPR_Count=44
//   proves the compiler sank loads next to uses, collapsing the batched
//   prefetch into per-group latency exposure. Fix: take the VMEM queue
//   away from the compiler entirely (AITER pattern):
//     - all loads/stores are asm volatile global_load/store_dword with
//       uniform SGPR base + voff=lane*4 (compiler can't re-roll or drain)
//     - 4 register tile buffers (TILE=32), prefetch distance 2
//     - ONE counted s_waitcnt vmcnt(32) per sub-step: retires
//       {stores(u-1), loads(u+1)}, leaves stores(u) in flight. Never 0.
//     - sched_barrier(0) after each waitcnt (rule #18: hipcc hoists
//       register-only consumers past asm waitcnts)
//     - double-buffered spike regs + keep-alive asm after the wait that
//       retires their stores (asm store data regs must stay allocated
//       until retirement; compiler can't track asm stores)
//   Steady state: 64-96 VMEM ops in flight/wave (16-24 KB) > ~10 KB
//   Little's-law need at target BW. Traffic floor: 201 MB @ ~6 TB/s
//   = ~33 us.
//
// Numerics MUST match numpy's fp32 rounding exactly (outputs are 0/1 spikes;
// a flipped spike = absmax 1.0): separate rounded mul/add (no FMA), and
// alpha = correctly-rounded float of exp(double(float(-0.05))).
// fire ? __fsub_rn(va,1.0f) : va is bitwise identical to va - spk.
// R0-R4 all passed with absmax == 0.0 — do not change the arithmetic.

constexpr int T_ = 2048;
constexpr int N_ = 512;
constexpr int TILE = 32;             // time steps per register tile
constexpr int NT = T_ / TILE;        // 64 tiles

// Issue TILE batched loads for tile TT into register array BUF.
// Uniform SGPR row base, per-lane voff. asm volatile => compiler cannot
// split, re-roll, or sink them.
#define GLOADTILE(BUF, TT)                                                   \
  {                                                                          \
    const float* gp_ = xq + (size_t)(TT) * TILE * N_;                        \
    _Pragma("unroll")                                                        \
    for (int i_ = 0; i_ < TILE; ++i_) {                                      \
      asm volatile("global_load_dword %0, %1, %2"                            \
                   : "=v"(BUF[i_])                                           \
                   : "v"(voff), "s"(gp_ + (size_t)i_ * N_));                 \
    }                                                                        \
  }

// Compute TILE scan steps from BUF (loads already retired by the counted
// waitcnt one sub-step earlier), write spikes into SPK regs and issue asm
// stores. Arithmetic identical to R0-R4 (verified absmax==0.0).
#define COMPUTE(BUF, SPK, TT)                                                \
  {                                                                          \
    const float* op_ = oq + (size_t)(TT) * TILE * N_;                        \
    _Pragma("unroll")                                                        \
    for (int j_ = 0; j_ < TILE; ++j_) {                                      \
      const float it_ = __fmul_rn(BUF[j_], w);                               \
      vsyn = __fadd_rn(__fmul_rn(alpha, vsyn), it_);                         \
      const float va_ = __fadd_rn(__fmul_rn(alpha, vmem), vsyn);             \
      const bool fire_ = (va_ >= 1.0f);                                      \
      SPK[j_] = fire_ ? 1.0f : 0.0f;                                         \
      asm volatile("global_store_dword %1, %0, %2"                           \
                   :: "v"(SPK[j_]), "v"(voff),                               \
                      "s"(op_ + (size_t)j_ * N_)                             \
                   : "memory");                                              \
      vmem = fire_ ? __fsub_rn(va_, 1.0f) : va_;                             \
    }                                                                        \
  }

// Keep asm-store data registers allocated until their stores have retired.
#define KEEPALIVE16(S, O)                                                    \
  asm volatile("" :: "v"(S[(O)+0]),  "v"(S[(O)+1]),  "v"(S[(O)+2]),          \
                     "v"(S[(O)+3]),  "v"(S[(O)+4]),  "v"(S[(O)+5]),          \
                     "v"(S[(O)+6]),  "v"(S[(O)+7]),  "v"(S[(O)+8]),          \
                     "v"(S[(O)+9]),  "v"(S[(O)+10]), "v"(S[(O)+11]),         \
                     "v"(S[(O)+12]), "v"(S[(O)+13]), "v"(S[(O)+14]),         \
                     "v"(S[(O)+15]))

// One pipeline sub-step for tile TT:
//   compute TT -> wait vmcnt(32) (retires stores(TT-1)+loads(TT+1),
//   leaves stores(TT)) -> sched fence -> release prev spike regs ->
//   issue loads for TT+2.
#define SUBSTEP(BUFC, SPKC, SPKP, BUFP, TT, DOPF)                            \
  {                                                                          \
    COMPUTE(BUFC, SPKC, TT);                                                 \
    asm volatile("s_waitcnt vmcnt(32)");                                     \
    __builtin_amdgcn_sched_barrier(0);                                       \
    KEEPALIVE16(SPKP, 0);                                                    \
    KEEPALIVE16(SPKP, 16);                                                   \
    if (DOPF) { GLOADTILE(BUFP, (TT) + 2); }                                 \
  }

__global__ __launch_bounds__(64, 1)
void exodus_asm_kernel(const float* __restrict__ x,
                       const float* __restrict__ wptr,
                       float* __restrict__ out) {
    const int blk  = blockIdx.x;          // 0..255
    const int b    = blk >> 3;            // 0..31
    const int n0   = (blk & 7) * 64;      // 0,64,...,448
    const int lane = threadIdx.x;         // 0..63 (block = 1 wave)

    // Uniform (SGPR) bases; lane handled by voff.
    const float* __restrict__ xq  = x   + (size_t)b * T_ * N_ + n0;
    float*       __restrict__ oq  = out + (size_t)b * T_ * N_ + n0;
    const unsigned voff = (unsigned)lane * 4u;

    const float w = wptr[0];
    const float alpha = (float)exp((double)(-1.0f / 20.0f));
    float vsyn = 0.0f, vmem = 0.0f;

    float B0[TILE], B1[TILE], B2[TILE], B3[TILE];
    float s0[TILE], s1[TILE];
#pragma unroll
    for (int j = 0; j < TILE; ++j) { s0[j] = 0.0f; s1[j] = 0.0f; }

    // Prologue: tiles 0 and 1 in flight; retire tile 0 only (counted wait).
    GLOADTILE(B0, 0);
    GLOADTILE(B1, 1);
    asm volatile("s_waitcnt vmcnt(32)");
    __builtin_amdgcn_sched_barrier(0);

    // Main loop: tiles 0..59, always prefetching TT+2.
    for (int t = 0; t < NT - 4; t += 4) {
        SUBSTEP(B0, s0, s1, B2, t + 0, true);
        SUBSTEP(B1, s1, s0, B3, t + 1, true);
        SUBSTEP(B2, s0, s1, B0, t + 2, true);
        SUBSTEP(B3, s1, s0, B1, t + 3, true);
    }
    // Tail: tiles 60..63 (prefetch 62,63; then none).
    SUBSTEP(B0, s0, s1, B2, NT - 4, true);
    SUBSTEP(B1, s1, s0, B3, NT - 3, true);
    SUBSTEP(B2, s0, s1, B0, NT - 2, false);
    SUBSTEP(B3, s1, s0, B1, NT - 1, false);
    // stores(NT-1) left in flight at endpgm: data regs are never
    // overwritten after issue, so this is safe.
}

extern "C" void kernel_launch(void* const* d_in, const int* in_sizes, int n_in,
                              void* d_out, int out_size, void* d_ws, size_t ws_size,
                              hipStream_t stream) {
    const float* x = (const float*)d_in[0];
    const float* w = (const float*)d_in[1];
    float* out = (float*)d_out;

    dim3 grid(256);    // one wave per CU; 64 sequences per block
    dim3 block(64);
    hipLaunchKernelGGL(exodus_asm_kernel, grid, block, 0, stream, x, w, out);
}

// Round 3
// 246.466 us; speedup vs baseline: 1.0491x; 1.0274x over previous
//
#include <hip/hip_runtime.h>
#include <math.h>

// ExodusNeuron: per-(b,n) sequential scan over T with spike threshold/reset.
// x: (B=32, T=2048, N=512, 1) fp32; weight: (1,1) fp32; out: (B,T,N,1) fp32.
//
// R6: compiler-visible register pipeline, scheduler-fenced.
//   R4 (plain C dbuf, 102us): compiler SANK the prefetch loads next to
//   their uses (VGPR=44 proves buffers never materialized).
//   R5 (raw asm loads, 95us): allocator SPILLED the opaque asm outputs
//   (VGPR=72 vs ~200 needed) and waitcnt insertion went conservative
//   around the asm. Both are the same collapsed pipeline, not a HW limit
//   (VALUBusy 7%, HBM 26%, floor is ~33us @ 201MB traffic).
//   Middle path: ordinary loads (compiler tracks vmcnt and emits COUNTED
//   waits, since consumers are 2 tiles downstream) + sched_barrier(0)
//   fences so the machine scheduler cannot re-sink the load batches
//   (rule #18 / m137 mechanism). 4 rotating TILE=32 buffers, prefetch
//   distance 2: ~1000cy of compute covers ~900cy HBM latency.
//   __launch_bounds__(64,1) -> 512-VGPR budget, no spill at ~170 live.
//
// Numerics MUST match numpy's fp32 rounding exactly (outputs are 0/1 spikes;
// a flipped spike = absmax 1.0): separate rounded mul/add (no FMA), and
// alpha = correctly-rounded float of exp(double(float(-0.05))).
// fire ? __fsub_rn(va,1.0f) : va is bitwise identical to va - spk.
// R0-R5 all passed with absmax == 0.0 — do not change the arithmetic.

constexpr int T_ = 2048;
constexpr int N_ = 512;
constexpr int TILE = 32;             // time steps per register tile
constexpr int NT = T_ / TILE;        // 64 tiles

#define SB() __builtin_amdgcn_sched_barrier(0)

// Batched compiler-visible loads for tile TT into register array BUF.
#define LOADTILE(BUF, TT)                                                    \
  {                                                                          \
    const float* __restrict__ g_ = xp + (size_t)(TT) * TILE * N_;            \
    _Pragma("unroll")                                                        \
    for (int i_ = 0; i_ < TILE; ++i_) BUF[i_] = g_[(size_t)i_ * N_];         \
  }

// 32 scan steps from BUF; spikes stored nontemporally (compiler-visible).
// Arithmetic identical to R0-R5 (verified absmax==0.0).
#define COMPUTETILE(BUF, TT)                                                 \
  {                                                                          \
    float* __restrict__ o_ = op + (size_t)(TT) * TILE * N_;                  \
    _Pragma("unroll")                                                        \
    for (int j_ = 0; j_ < TILE; ++j_) {                                      \
      const float it_ = __fmul_rn(BUF[j_], w);                               \
      vsyn = __fadd_rn(__fmul_rn(alpha, vsyn), it_);                         \
      const float va_ = __fadd_rn(__fmul_rn(alpha, vmem), vsyn);             \
      const bool fire_ = (va_ >= 1.0f);                                      \
      __builtin_nontemporal_store(fire_ ? 1.0f : 0.0f,                       \
                                  o_ + (size_t)j_ * N_);                     \
      vmem = fire_ ? __fsub_rn(va_, 1.0f) : va_;                             \
    }                                                                        \
  }

__global__ __launch_bounds__(64, 1)
void exodus_pipe_kernel(const float* __restrict__ x,
                        const float* __restrict__ wptr,
                        float* __restrict__ out) {
    const int blk  = blockIdx.x;          // 0..255
    const int b    = blk >> 3;            // 0..31
    const int n0   = (blk & 7) * 64;      // 0,64,...,448
    const int lane = threadIdx.x;         // 0..63 (block = 1 wave)

    const size_t base = (size_t)b * T_ * N_ + (size_t)n0 + lane;
    const float* __restrict__ xp = x + base;
    float* __restrict__ op = out + base;

    const float w = wptr[0];
    const float alpha = (float)exp((double)(-1.0f / 20.0f));
    float vsyn = 0.0f, vmem = 0.0f;

    float B0[TILE], B1[TILE], B2[TILE], B3[TILE];

    // Prologue: tiles 0 and 1 in flight.
    LOADTILE(B0, 0);
    SB();
    LOADTILE(B1, 1);
    SB();

    // Steady state, 4-tile rotation, prefetch distance 2.
    // Issue L(t+2) right before compute(t): compute(t)+compute(t+1)
    // (~1000cy) covers the load latency before compute(t+2) reads it.
    for (int t = 0; t < NT; t += 4) {
        LOADTILE(B2, t + 2);              // t+2 <= 62 always
        SB();
        COMPUTETILE(B0, t + 0);
        SB();
        LOADTILE(B3, t + 3);              // t+3 <= 63 always
        SB();
        COMPUTETILE(B1, t + 1);
        SB();
        if (t + 4 < NT) { LOADTILE(B0, t + 4); }
        SB();
        COMPUTETILE(B2, t + 2);
        SB();
        if (t + 5 < NT) { LOADTILE(B1, t + 5); }
        SB();
        COMPUTETILE(B3, t + 3);
        SB();
    }
}

extern "C" void kernel_launch(void* const* d_in, const int* in_sizes, int n_in,
                              void* d_out, int out_size, void* d_ws, size_t ws_size,
                              hipStream_t stream) {
    const float* x = (const float*)d_in[0];
    const float* w = (const float*)d_in[1];
    float* out = (float*)d_out;

    dim3 grid(256);    // one wave per CU; 64 sequences per block
    dim3 block(64);
    hipLaunchKernelGGL(exodus_pipe_kernel, grid, block, 0, stream, x, w, out);
}

// Round 4
// 239.176 us; speedup vs baseline: 1.0810x; 1.0305x over previous
//
#include <hip/hip_runtime.h>
#include <math.h>

// ExodusNeuron: per-(b,n) sequential scan over T with spike threshold/reset.
// x: (B=32, T=2048, N=512, 1) fp32; weight: (1,1) fp32; out: (B,T,N,1) fp32.
//
// R7: DMA producer + direct-store consumer, raw barriers, counted waits.
//   History: R3 (LDS prod/cons, __syncthreads) = 82us — killed by the
//   implicit s_waitcnt vmcnt(0) lgkmcnt(0) before every barrier (producers
//   drained spike STORES in the critical path, 64x/block). R4/R5/R6
//   (register pipelines) = 95-113us — VGPR_Count 44/72/80 proves the
//   backend never keeps 4x32 load results live; the pipeline collapses
//   no matter how loads are expressed (C, asm, sched-fenced).
//   Fix both structurally:
//     - producer wave stages tiles via __builtin_amdgcn_global_load_lds
//       (no VGPRs to spill, no SSA to sink; tracked by vmcnt). Its VMEM
//       stream contains ONLY these DMAs -> "s_waitcnt vmcnt(0)" confirms
//       a tile without draining any stores, overlapped with consumer
//       compute (~1100cy hidden under ~1700cy).
//     - consumer stores spikes DIRECTLY to global (nontemporal); its
//       vmcnt is never waited on. No SBUF, no store drain anywhere.
//     - raw __builtin_amdgcn_s_barrier() (does NOT force waitcnt drains,
//       verified by the 8-phase GEMM template) + sched_barrier(0) fences.
//   DMA layout requirement (m104/m108): LDS dest = wave-uniform row base
//   + lane*4; global src = row base + lane*4 contiguous. Exactly our
//   pattern: XBUF[bb][j][lane] <- x[b, t*64+j, n0+lane].
//
// Numerics MUST match numpy's fp32 rounding exactly (outputs are 0/1 spikes;
// a flipped spike = absmax 1.0): separate rounded mul/add (no FMA), and
// alpha = correctly-rounded float of exp(double(float(-0.05))).
// fire ? __fsub_rn(va,1.0f) : va is bitwise identical to va - spk.
// R0-R6 all passed with absmax == 0.0 — do not change the arithmetic.

constexpr int T_ = 2048;
constexpr int N_ = 512;
constexpr int TILE = 64;             // time steps per staged tile
constexpr int NTILE = T_ / TILE;     // 32 tiles
constexpr int NCH = 64;              // neurons per block (one per lane)

typedef const __attribute__((address_space(1))) void* gas_ptr;
typedef __attribute__((address_space(3))) void* las_ptr;

__global__ __launch_bounds__(128, 1)
void exodus_dma_kernel(const float* __restrict__ x,
                       const float* __restrict__ wptr,
                       float* __restrict__ out) {
    __shared__ float XBUF[2][TILE][NCH];     // 32 KB, double-buffered input

    const int blk  = blockIdx.x;             // 0..255
    const int b    = blk >> 3;               // 0..31
    const int n0   = (blk & 7) * NCH;        // 0,64,...,448
    const int wave = threadIdx.x >> 6;       // 0 = consumer, 1 = producer
    const int lane = threadIdx.x & 63;

    const size_t base = (size_t)b * T_ * N_ + (size_t)n0 + lane;

    if (wave == 1) {
        // ================= producer: pure DMA issuer =================
        const float* __restrict__ xp = x + base;   // includes +lane

        // prologue: stage tile 0, confirm, publish
        {
            const float* __restrict__ g = xp;
#pragma unroll
            for (int j = 0; j < TILE; ++j) {
                __builtin_amdgcn_global_load_lds(
                    (gas_ptr)(g + (size_t)j * N_),
                    (las_ptr)&XBUF[0][j][0], 4, 0, 0);
            }
        }
        __builtin_amdgcn_sched_barrier(0);
        asm volatile("s_waitcnt vmcnt(0)");
        __builtin_amdgcn_sched_barrier(0);
        __builtin_amdgcn_s_barrier();

        for (int t = 0; t < NTILE; ++t) {
            if (t + 1 < NTILE) {
                const float* __restrict__ g =
                    xp + (size_t)(t + 1) * TILE * N_;
                const int bb = (t + 1) & 1;
#pragma unroll
                for (int j = 0; j < TILE; ++j) {
                    __builtin_amdgcn_global_load_lds(
                        (gas_ptr)(g + (size_t)j * N_),
                        (las_ptr)&XBUF[bb][j][0], 4, 0, 0);
                }
                __builtin_amdgcn_sched_barrier(0);
                // only DMAs live in this wave's vmcnt: this confirms the
                // tile landed in LDS. Latency hidden under consumer's
                // compute of tile t (different wave).
                asm volatile("s_waitcnt vmcnt(0)");
                __builtin_amdgcn_sched_barrier(0);
            }
            __builtin_amdgcn_s_barrier();
        }
    } else {
        // ================= consumer: compute + direct stores =========
        float* __restrict__ op = out + base;
        const float w = wptr[0];
        const float alpha = (float)exp((double)(-1.0f / 20.0f));
        float vsyn = 0.0f, vmem = 0.0f;

        __builtin_amdgcn_s_barrier();       // matches producer prologue

        for (int t = 0; t < NTILE; ++t) {
            const int bb = t & 1;
            __builtin_amdgcn_sched_barrier(0);  // keep reads after barrier

            // batched LDS reads: stride 256B -> 2 lanes/bank (free)
            float xv[TILE];
#pragma unroll
            for (int j = 0; j < TILE; ++j) xv[j] = XBUF[bb][j][lane];

            float* __restrict__ o = op + (size_t)t * TILE * N_;
#pragma unroll
            for (int j = 0; j < TILE; ++j) {
                const float i_t = __fmul_rn(xv[j], w);
                vsyn = __fadd_rn(__fmul_rn(alpha, vsyn), i_t);
                const float va = __fadd_rn(__fmul_rn(alpha, vmem), vsyn);
                const bool fire = (va >= 1.0f);
                // direct nontemporal store; consumer vmcnt never waited
                __builtin_nontemporal_store(fire ? 1.0f : 0.0f,
                                            o + (size_t)j * N_);
                vmem = fire ? __fsub_rn(va, 1.0f) : va;   // == va - spk
            }
            __builtin_amdgcn_sched_barrier(0);
            __builtin_amdgcn_s_barrier();
        }
    }
}

extern "C" void kernel_launch(void* const* d_in, const int* in_sizes, int n_in,
                              void* d_out, int out_size, void* d_ws, size_t ws_size,
                              hipStream_t stream) {
    const float* x = (const float*)d_in[0];
    const float* w = (const float*)d_in[1];
    float* out = (float*)d_out;

    dim3 grid(256);    // one block per CU; 64 sequences per block
    dim3 block(128);   // wave 0 = consumer, wave 1 = DMA producer
    hipLaunchKernelGGL(exodus_dma_kernel, grid, block, 0, stream, x, w, out);
}

// Round 5
// 238.220 us; speedup vs baseline: 1.0854x; 1.0040x over previous
//
#include <hip/hip_runtime.h>
#include <math.h>

// ExodusNeuron: per-(b,n) sequential scan over T with spike threshold/reset.
// x: (B=32, T=2048, N=512, 1) fp32; weight: (1,1) fp32; out: (B,T,N,1) fp32.
//
// R8: DMA producer with WIDTH-16 loads + DEPTH-2 counted-vmcnt pipeline.
//   R7 (width-4 DMA, depth-1, vmcnt(0)/tile) = 85us: each tile paid the
//   full batch-completion latency (~2500-6000cy under machine-wide
//   queueing) minus ~1800cy of consumer overlap. All of R3-R7 were
//   effectively depth<=1 and converged at 82-113us; VALUBusy 10%/HBM 29%
//   says nothing is saturated. Two fixes (T3+T4 pattern):
//     1) global_load_lds width=16: global src addr is PER-LANE (guide
//        m173: pre-swizzled-source pattern), LDS dest = base + lane*16.
//        lane l reads 16B of 4 neurons from time-row j0+(l>>4) =>
//        ONE instruction stages 4 time-rows (1KB). 16 instrs/tile vs 64.
//     2) depth-2: steady state keeps tiles t+1 AND t+2 in flight
//        (32 DMAs); per iter: issue L(t+2) then s_waitcnt vmcnt(16)
//        (confirms t+1, leaves t+2 flying). Never drain to 0 mid-loop.
//   4 LDS buffers (64KB). Raw s_barrier (no implicit drains) +
//   sched_barrier(0) fences (rule #18). Consumer: batched ds_reads
//   (256B stride = 2-way bank alias = free), direct nontemporal global
//   stores, its vmcnt is never waited.
//
// Numerics MUST match numpy's fp32 rounding exactly (outputs are 0/1 spikes;
// a flipped spike = absmax 1.0): separate rounded mul/add (no FMA), and
// alpha = correctly-rounded float of exp(double(float(-0.05))).
// fire ? __fsub_rn(va,1.0f) : va is bitwise identical to va - spk.
// R0-R7 all passed with absmax == 0.0 — do not change the arithmetic.

constexpr int T_ = 2048;
constexpr int N_ = 512;
constexpr int TILE = 64;             // time steps per staged tile
constexpr int NTILE = T_ / TILE;     // 32 tiles
constexpr int NCH = 64;              // neurons per block (one per lane)
constexpr int NBUF = 4;              // LDS tile buffers (depth-2 + slack)

typedef const __attribute__((address_space(1))) void* gas_ptr;
typedef __attribute__((address_space(3))) void* las_ptr;

__global__ __launch_bounds__(128, 1)
void exodus_dma2_kernel(const float* __restrict__ x,
                        const float* __restrict__ wptr,
                        float* __restrict__ out) {
    __shared__ float XBUF[NBUF][TILE][NCH];   // 64 KB

    const int blk  = blockIdx.x;             // 0..255
    const int b    = blk >> 3;               // 0..31
    const int n0   = (blk & 7) * NCH;        // 0,64,...,448
    const int wave = threadIdx.x >> 6;       // 0 = consumer, 1 = producer
    const int lane = threadIdx.x & 63;

    if (wave == 1) {
        // ============ producer: width-16 DMA, depth-2 pipeline ============
        // lane l covers 16B (4 neurons) of time-row (l>>4) within each
        // 4-row group: global addr = row(j0 + (l>>4)) + n0*4 + (l&15)*16.
        const int plane = lane >> 4;          // 0..3  (time-row within group)
        const int sub   = lane & 15;          // 0..15 (16B chunk within row)
        const float* __restrict__ gl =
            x + (size_t)b * T_ * N_ + (size_t)plane * N_ + n0 + sub * 4;

        // Stage tile TT into buffer (TT & 3): 16 width-16 DMAs
        // (j0 = 0,4,...,60), each moves 4 time-rows = 1KB.
#define ISSUE_TILE(TT)                                                        \
        {                                                                     \
            const float* __restrict__ g_ =                                    \
                gl + (size_t)(TT) * TILE * N_;                                \
            _Pragma("unroll")                                                 \
            for (int j0_ = 0; j0_ < TILE; j0_ += 4) {                         \
                __builtin_amdgcn_global_load_lds(                             \
                    (gas_ptr)(g_ + (size_t)j0_ * N_),                         \
                    (las_ptr)&XBUF[(TT) & (NBUF - 1)][j0_][0], 16, 0, 0);     \
            }                                                                 \
        }

        // prologue: tiles 0 and 1 in flight; confirm tile 0 only.
        ISSUE_TILE(0);
        ISSUE_TILE(1);
        __builtin_amdgcn_sched_barrier(0);
        asm volatile("s_waitcnt vmcnt(16)");   // tile 0 landed; tile 1 flies
        __builtin_amdgcn_sched_barrier(0);
        __builtin_amdgcn_s_barrier();          // barrier 0

        for (int t = 0; t < NTILE; ++t) {
            if (t + 2 < NTILE) {
                ISSUE_TILE(t + 2);
                __builtin_amdgcn_sched_barrier(0);
                // outstanding = 32 (tiles t+1, t+2); confirm oldest 16
                // = tile t+1, leave t+2 in flight.
                asm volatile("s_waitcnt vmcnt(16)");
            } else {
                // tail: confirm whatever remains (tile NTILE-1 or none)
                asm volatile("s_waitcnt vmcnt(0)");
            }
            __builtin_amdgcn_sched_barrier(0);
            __builtin_amdgcn_s_barrier();      // barrier t+1
        }
#undef ISSUE_TILE
    } else {
        // ============ consumer: compute + direct nontemporal stores =======
        const size_t base = (size_t)b * T_ * N_ + (size_t)n0 + lane;
        float* __restrict__ op = out + base;
        const float w = wptr[0];
        const float alpha = (float)exp((double)(-1.0f / 20.0f));
        float vsyn = 0.0f, vmem = 0.0f;

        __builtin_amdgcn_s_barrier();          // barrier 0 (tile 0 ready)

        for (int t = 0; t < NTILE; ++t) {
            const int bb = t & (NBUF - 1);
            __builtin_amdgcn_sched_barrier(0); // keep reads after barrier

            // batched LDS reads: stride 256B -> 2 lanes/bank (free)
            float xv[TILE];
#pragma unroll
            for (int j = 0; j < TILE; ++j) xv[j] = XBUF[bb][j][lane];

            float* __restrict__ o = op + (size_t)t * TILE * N_;
#pragma unroll
            for (int j = 0; j < TILE; ++j) {
                const float i_t = __fmul_rn(xv[j], w);
                vsyn = __fadd_rn(__fmul_rn(alpha, vsyn), i_t);
                const float va = __fadd_rn(__fmul_rn(alpha, vmem), vsyn);
                const bool fire = (va >= 1.0f);
                // direct nontemporal store; consumer vmcnt never waited
                __builtin_nontemporal_store(fire ? 1.0f : 0.0f,
                                            o + (size_t)j * N_);
                vmem = fire ? __fsub_rn(va, 1.0f) : va;   // == va - spk
            }
            __builtin_amdgcn_sched_barrier(0);
            __builtin_amdgcn_s_barrier();      // barrier t+1
        }
    }
}

extern "C" void kernel_launch(void* const* d_in, const int* in_sizes, int n_in,
                              void* d_out, int out_size, void* d_ws, size_t ws_size,
                              hipStream_t stream) {
    const float* x = (const float*)d_in[0];
    const float* w = (const float*)d_in[1];
    float* out = (float*)d_out;

    dim3 grid(256);    // one block per CU; 64 sequences per block
    dim3 block(128);   // wave 0 = consumer, wave 1 = width-16 DMA producer
    hipLaunchKernelGGL(exodus_dma2_kernel, grid, block, 0, stream, x, w, out);
}